// Round 7
// baseline (348.653 us; speedup 1.0000x reference)
//
#include <hip/hip_runtime.h>

#define B_ 8
#define N_ 20000
#define M_ 1024
#define C_ 128
#define S_ 64
#define NCH_ 131   // 3 + C
#define TILE_ 512  // points per wave-iteration (8 per lane)
#define NT_ ((N_ + TILE_ - 1) / TILE_)   // 40 tiles

typedef float  vf4 __attribute__((ext_vector_type(4)));  // nontemporal-compatible 16B

// ---- K1: ball query, 3-deep software-pipelined 512-pt tiles ----------------
__global__ __launch_bounds__(256, 4) void query_kernel(
    const float* __restrict__ xyz,       // (B, N, 3)
    const float* __restrict__ new_xyz,   // (B, M, 3)
    float* __restrict__ out,
    int* __restrict__ iws)               // (B, M, S) int scratch
{
    const int wid  = threadIdx.x >> 6;
    const int lane = threadIdx.x & 63;
    const int bm   = blockIdx.x * 4 + wid;
    const int b    = bm >> 10;
    const int m    = bm & (M_ - 1);

    __shared__ int s_idx[4][S_];

    const float cx = new_xyz[bm * 3 + 0];
    const float cy = new_xyz[bm * 3 + 1];
    const float cz = new_xyz[bm * 3 + 2];
    const float r2 = (float)(0.3 * 0.3);
    const float* xb = xyz + (size_t)b * N_ * 3;
    const unsigned long long below = (1ull << lane) - 1ull;

// load one 512-pt tile into 24 regs (6 independent float4 loads, 16B aligned)
#define LOAD_TILE(F, INB, NB, BASE) do {                                      \
    NB = (BASE) + 8 * lane;                                                   \
    INB = (NB < N_);   /* N_%8==0: all 8 of this lane in-range iff INB */     \
    if (INB) {                                                                \
        const float4* p4_ = (const float4*)(xb + (size_t)NB * 3);             \
        _Pragma("unroll")                                                     \
        for (int q = 0; q < 6; ++q) {                                         \
            const float4 v_ = p4_[q];                                         \
            F[4*q+0] = v_.x; F[4*q+1] = v_.y; F[4*q+2] = v_.z; F[4*q+3] = v_.w; \
        }                                                                     \
    } } while (0)

// process one tile: exact numpy f32 rounding (no FMA contraction)
#define PROC_TILE(F, INB, NB) do {                                            \
    unsigned vbits = 0;                                                       \
    if (INB) {                                                                \
        _Pragma("unroll")                                                     \
        for (int j = 0; j < 8; ++j) {                                         \
            const float dx = __fadd_rn(F[3*j+0], -cx);                        \
            const float dy = __fadd_rn(F[3*j+1], -cy);                        \
            const float dz = __fadd_rn(F[3*j+2], -cz);                        \
            const float d2 = __fadd_rn(                                       \
                __fadd_rn(__fmul_rn(dx, dx), __fmul_rn(dy, dy)),              \
                __fmul_rn(dz, dz));                                           \
            if (d2 < r2) vbits |= (1u << j);                                  \
        }                                                                     \
    }                                                                         \
    int pre = 0, tot = 0;                                                     \
    _Pragma("unroll")                                                         \
    for (int j = 0; j < 8; ++j) {                                             \
        const unsigned long long mk = __ballot((vbits >> j) & 1u);            \
        pre += __popcll(mk & below);                                          \
        tot += __popcll(mk);                                                  \
    }                                                                         \
    int pos = cnt + pre;                                                      \
    _Pragma("unroll")                                                         \
    for (int j = 0; j < 8; ++j) {                                             \
        if (vbits & (1u << j)) {                                              \
            if (pos < S_) s_idx[wid][pos] = NB + j;                           \
            ++pos;                                                            \
        }                                                                     \
    }                                                                         \
    cnt += tot; } while (0)

// one pipeline stage: prefetch tile t_load into R (distance 2), process P
#define STAGE(PF, PINB, PNB, RF, RINB, RNB) do {                              \
    if (t_load < NT_) { LOAD_TILE(RF, RINB, RNB, t_load * TILE_); }           \
    ++t_load;                                                                 \
    PROC_TILE(PF, PINB, PNB);                                                 \
    ++t_proc;                                                                 \
    if (cnt >= S_ || t_proc >= NT_) goto qdone;                               \
    } while (0)

    int cnt = 0;
    float fA[24], fB[24], fC[24];
    bool inbA = false, inbB = false, inbC = false;
    int nA = 0, nB = 0, nC = 0;

    // prologue: tiles 0 and 1 in flight (NT_ >= 2 always here)
    LOAD_TILE(fA, inbA, nA, 0 * TILE_);
    LOAD_TILE(fB, inbB, nB, 1 * TILE_);
    int t_load = 2, t_proc = 0;

    for (;;) {
        STAGE(fA, inbA, nA, fC, inbC, nC);   // proc 0, load 2
        STAGE(fB, inbB, nB, fA, inbA, nA);   // proc 1, load 3
        STAGE(fC, inbC, nC, fB, inbB, nB);   // proc 2, load 4
    }
qdone:
#undef LOAD_TILE
#undef PROC_TILE
#undef STAGE

    {
        const int c = cnt < S_ ? cnt : S_;
        const int first = (c > 0) ? s_idx[wid][0] : 0;
        if (lane >= c) s_idx[wid][lane] = first;

        const int n = s_idx[wid][lane];

        // idx outputs (float copy in d_out, int copy for K2 -- keep iws L2-cached)
        float* out_idx = out + (size_t)B_ * NCH_ * M_ * S_;
        __builtin_nontemporal_store((float)n, &out_idx[(size_t)bm * S_ + lane]);
        iws[(size_t)bm * S_ + lane] = n;

        // grouped relative xyz -> channels 0..2 (xyz L2-hot; coalesced 256B)
        const float px = xb[n * 3 + 0];
        const float py = xb[n * 3 + 1];
        const float pz = xb[n * 3 + 2];
        __builtin_nontemporal_store((px - cx) / 0.3f,
            &out[(((size_t)b * NCH_ + 0) * M_ + m) * S_ + lane]);
        __builtin_nontemporal_store((py - cy) / 0.3f,
            &out[(((size_t)b * NCH_ + 1) * M_ + m) * S_ + lane]);
        __builtin_nontemporal_store((pz - cz) / 0.3f,
            &out[(((size_t)b * NCH_ + 2) * M_ + m) * S_ + lane]);
    }
}

// ---- K2: per (b,ch) block -- stage 80KB channel slice in LDS, gather-write -
__global__ __launch_bounds__(256) void group_feat_kernel(
    const float* __restrict__ features,  // (B, C, N)
    const int* __restrict__ iws,         // (B, M, S)
    float* __restrict__ out)
{
    // b = blockIdx & 7: round-robin dispatch pins each batch to one XCD,
    // keeping that batch's idx slice (256 KB) L2-resident.
    const int b  = blockIdx.x & 7;
    const int ch = blockIdx.x >> 3;

    __shared__ float slice[N_];          // 80000 B (gfx950: >64KB LDS ok)

    const float* fb = features + ((size_t)b * C_ + ch) * N_;
    const vf4* fb4 = (const vf4*)fb;
    vf4* sl4 = (vf4*)slice;
    for (int i = threadIdx.x; i < N_ / 4; i += 256)
        sl4[i] = __builtin_nontemporal_load(&fb4[i]);  // read-once stream
    __syncthreads();

    const int* ib = iws + (size_t)b * M_ * S_;
    float* ob = out + ((size_t)b * NCH_ + 3 + ch) * (size_t)(M_ * S_);
    // 4 elems/thread: int4 idx load + float4 nontemporal store (streamed out)
    for (int e = threadIdx.x * 4; e < M_ * S_; e += 256 * 4) {
        const int4 ii = *(const int4*)(ib + e);
        vf4 w;
        w.x = slice[ii.x]; w.y = slice[ii.y];
        w.z = slice[ii.z]; w.w = slice[ii.w];
        __builtin_nontemporal_store(w, (vf4*)(ob + e));
    }
}

// ---- Fallback: round-1 fused kernel (if ws too small) ----------------------
__global__ __launch_bounds__(256) void qg_fused(
    const float* __restrict__ xyz,
    const float* __restrict__ new_xyz,
    const float* __restrict__ features,
    float* __restrict__ out)
{
    const int bm = blockIdx.x;
    const int b  = bm >> 10;
    const int m  = bm & (M_ - 1);
    const int tid = threadIdx.x;

    __shared__ int s_idx[S_];

    if (tid < 64) {
        const int lane = tid;
        const float cx = new_xyz[bm * 3 + 0];
        const float cy = new_xyz[bm * 3 + 1];
        const float cz = new_xyz[bm * 3 + 2];
        const float r2 = (float)(0.3 * 0.3);
        const float* xb = xyz + (size_t)b * N_ * 3;

        int cnt = 0;
        for (int base = 0; base < N_; base += 64) {
            const int n = base + lane;
            bool valid = false;
            if (n < N_) {
                const float dx = __fadd_rn(xb[n * 3 + 0], -cx);
                const float dy = __fadd_rn(xb[n * 3 + 1], -cy);
                const float dz = __fadd_rn(xb[n * 3 + 2], -cz);
                const float d2 = __fadd_rn(
                    __fadd_rn(__fmul_rn(dx, dx), __fmul_rn(dy, dy)),
                    __fmul_rn(dz, dz));
                valid = d2 < r2;
            }
            const unsigned long long mk = __ballot(valid);
            if (valid) {
                const int pos = cnt + __popcll(mk & ((1ull << lane) - 1ull));
                if (pos < S_) s_idx[pos] = n;
            }
            cnt += __popcll(mk);
            if (cnt >= S_) break;
        }
        const int c = cnt < S_ ? cnt : S_;
        const int first = (c > 0) ? s_idx[0] : 0;
        if (lane >= c) s_idx[lane] = first;

        float* out_idx = out + (size_t)B_ * NCH_ * M_ * S_;
        out_idx[(size_t)bm * S_ + lane] = (float)s_idx[lane];
    }
    __syncthreads();

    if (tid < 3 * S_) {
        const int ch = tid >> 6;
        const int s  = tid & 63;
        const int n  = s_idx[s];
        const float v = (xyz[((size_t)b * N_ + n) * 3 + ch] - new_xyz[bm * 3 + ch]) / 0.3f;
        out[(((size_t)b * NCH_ + ch) * M_ + m) * S_ + s] = v;
    }

    const int s  = tid & 63;
    const int cq = tid >> 6;
    const int n  = s_idx[s];
    const float* fb = features + (size_t)b * C_ * N_;
    float* ob = out + (((size_t)b * NCH_ + 3) * M_ + m) * S_ + s;
    for (int ch = cq; ch < C_; ch += 4) {
        ob[(size_t)ch * (M_ * S_)] = fb[(size_t)ch * N_ + n];
    }
}

extern "C" void kernel_launch(void* const* d_in, const int* in_sizes, int n_in,
                              void* d_out, int out_size, void* d_ws, size_t ws_size,
                              hipStream_t stream) {
    const float* xyz      = (const float*)d_in[0];
    const float* new_xyz  = (const float*)d_in[1];
    // d_in[2] = batch_distances, d_in[3] = inds : acceleration hints only, unused
    const float* features = (const float*)d_in[4];
    float* out = (float*)d_out;

    const size_t need = (size_t)B_ * M_ * S_ * sizeof(int);  // 2 MB
    if (ws_size < need) {
        qg_fused<<<B_ * M_, 256, 0, stream>>>(xyz, new_xyz, features, out);
        return;
    }
    int* iws = (int*)d_ws;

    query_kernel<<<(B_ * M_) / 4, 256, 0, stream>>>(xyz, new_xyz, out, iws);
    group_feat_kernel<<<B_ * C_, 256, 0, stream>>>(features, iws, out);
}

// Round 8
// 131.228 us; speedup vs baseline: 2.6569x; 2.6569x over previous
//
#include <hip/hip_runtime.h>

#define B_ 8
#define N_ 20000
#define M_ 1024
#define C_ 128
#define S_ 64
#define NCH_ 131    // 3 + C
#define CHUNK_ 2048 // points per block-iteration (4 waves x 512)
#define NCHK_ ((N_ + CHUNK_ - 1) / CHUNK_)  // 10 chunks

typedef float  vf4 __attribute__((ext_vector_type(4)));  // nontemporal-compatible 16B

// ---- K1: ball query, block-cooperative (4 waves per center), 2-deep pipe ---
__global__ __launch_bounds__(256) void query_kernel(
    const float* __restrict__ xyz,       // (B, N, 3)
    const float* __restrict__ new_xyz,   // (B, M, 3)
    float* __restrict__ out,
    int* __restrict__ iws)               // (B, M, S) int scratch
{
    const int tid  = threadIdx.x;
    const int wid  = tid >> 6;
    const int lane = tid & 63;
    const int bm   = blockIdx.x;         // one block per center
    const int b    = bm >> 10;
    const int m    = bm & (M_ - 1);

    __shared__ int s_idx[S_];
    __shared__ int s_tot[2][4];          // per-wave totals, double-buffered

    const float cx = new_xyz[bm * 3 + 0];
    const float cy = new_xyz[bm * 3 + 1];
    const float cz = new_xyz[bm * 3 + 2];
    const float r2 = (float)(0.3 * 0.3);
    const float* xb = xyz + (size_t)b * N_ * 3;
    const unsigned long long below = (1ull << lane) - 1ull;

// load this wave's 512-pt slice of one chunk into 24 regs (6 float4, 16B-aligned)
#define LOAD_TILE(F, INB, NB, CB) do {                                        \
    NB = (CB) + (wid << 9) + (lane << 3);                                     \
    INB = (NB < N_);   /* N_%8==0: all 8 of this lane in-range iff INB */     \
    if (INB) {                                                                \
        const float4* p4_ = (const float4*)(xb + (size_t)NB * 3);             \
        _Pragma("unroll")                                                     \
        for (int q = 0; q < 6; ++q) {                                         \
            const float4 v_ = p4_[q];                                         \
            F[4*q+0] = v_.x; F[4*q+1] = v_.y; F[4*q+2] = v_.z; F[4*q+3] = v_.w; \
        }                                                                     \
    } } while (0)

// process one chunk: exact numpy f32 rounding (no FMA contraction);
// block-ordered compaction: pos = cnt + lower-wave totals + in-wave prefix
#define PROC_TILE(F, INB, NB, PAR) do {                                       \
    unsigned vbits = 0;                                                       \
    if (INB) {                                                                \
        _Pragma("unroll")                                                     \
        for (int j = 0; j < 8; ++j) {                                         \
            const float dx = __fadd_rn(F[3*j+0], -cx);                        \
            const float dy = __fadd_rn(F[3*j+1], -cy);                        \
            const float dz = __fadd_rn(F[3*j+2], -cz);                        \
            const float d2 = __fadd_rn(                                       \
                __fadd_rn(__fmul_rn(dx, dx), __fmul_rn(dy, dy)),              \
                __fmul_rn(dz, dz));                                           \
            if (d2 < r2) vbits |= (1u << j);                                  \
        }                                                                     \
    }                                                                         \
    int pre = 0, tot = 0;                                                     \
    _Pragma("unroll")                                                         \
    for (int j = 0; j < 8; ++j) {                                             \
        const unsigned long long mk = __ballot((vbits >> j) & 1u);            \
        pre += __popcll(mk & below);                                          \
        tot += __popcll(mk);                                                  \
    }                                                                         \
    if (lane == 0) s_tot[PAR][wid] = tot;                                     \
    __syncthreads();                                                          \
    int off = cnt;                                                            \
    _Pragma("unroll")                                                         \
    for (int w = 0; w < 4; ++w) { if (w < wid) off += s_tot[PAR][w]; }        \
    int pos = off + pre;                                                      \
    _Pragma("unroll")                                                         \
    for (int j = 0; j < 8; ++j) {                                             \
        if (vbits & (1u << j)) {                                              \
            if (pos < S_) s_idx[pos] = NB + j;                                \
            ++pos;                                                            \
        }                                                                     \
    }                                                                         \
    cnt += s_tot[PAR][0] + s_tot[PAR][1] + s_tot[PAR][2] + s_tot[PAR][3];     \
    } while (0)

// one pipeline stage: prefetch chunk t_load into R, process P (parity PAR)
#define STAGE(PF, PINB, PNB, RF, RINB, RNB, PAR) do {                         \
    if (t_load < NCHK_) { LOAD_TILE(RF, RINB, RNB, t_load * CHUNK_); }        \
    ++t_load;                                                                 \
    PROC_TILE(PF, PINB, PNB, PAR);                                            \
    ++t_proc;                                                                 \
    if (cnt >= S_ || t_proc >= NCHK_) goto qdone;                             \
    } while (0)

    int cnt = 0;
    float fA[24], fB[24];
    bool inbA = false, inbB = false;
    int nA = 0, nB = 0;

    LOAD_TILE(fA, inbA, nA, 0);
    int t_load = 1, t_proc = 0;

    for (;;) {
        STAGE(fA, inbA, nA, fB, inbB, nB, 0);   // proc even chunk, load next
        STAGE(fB, inbB, nB, fA, inbA, nA, 1);   // proc odd chunk, load next
    }
qdone:
#undef LOAD_TILE
#undef PROC_TILE
#undef STAGE

    __syncthreads();   // all s_idx writes visible block-wide
    {
        const int c = cnt < S_ ? cnt : S_;
        const int first = (c > 0) ? s_idx[0] : 0;
        if (tid >= c && tid < S_) s_idx[tid] = first;
    }
    __syncthreads();

    if (tid < S_) {
        const int n = s_idx[tid];
        // idx outputs (float copy in d_out, int copy for K2 -- keep iws L2-hot)
        float* out_idx = out + (size_t)B_ * NCH_ * M_ * S_;
        __builtin_nontemporal_store((float)n, &out_idx[(size_t)bm * S_ + tid]);
        iws[(size_t)bm * S_ + tid] = n;
    }
    if (tid < 3 * S_) {
        const int ch = tid >> 6;             // 0..2
        const int s  = tid & 63;
        const int n  = s_idx[s];
        const float cc = new_xyz[bm * 3 + ch];
        const float v = (xb[n * 3 + ch] - cc) / 0.3f;
        __builtin_nontemporal_store(v,
            &out[(((size_t)b * NCH_ + ch) * M_ + m) * S_ + s]);
    }
}

// ---- K2: per (b,ch) block -- stage 80KB channel slice in LDS, gather-write -
__global__ __launch_bounds__(256) void group_feat_kernel(
    const float* __restrict__ features,  // (B, C, N)
    const int* __restrict__ iws,         // (B, M, S)
    float* __restrict__ out)
{
    // b = blockIdx & 7: round-robin dispatch pins each batch to one XCD,
    // keeping that batch's idx slice (256 KB) L2-resident.
    const int b  = blockIdx.x & 7;
    const int ch = blockIdx.x >> 3;

    __shared__ float slice[N_];          // 80000 B (gfx950: >64KB LDS ok)

    const float* fb = features + ((size_t)b * C_ + ch) * N_;
    const vf4* fb4 = (const vf4*)fb;
    vf4* sl4 = (vf4*)slice;
    for (int i = threadIdx.x; i < N_ / 4; i += 256)
        sl4[i] = __builtin_nontemporal_load(&fb4[i]);  // read-once stream
    __syncthreads();

    const int* ib = iws + (size_t)b * M_ * S_;
    float* ob = out + ((size_t)b * NCH_ + 3 + ch) * (size_t)(M_ * S_);
    // 4 elems/thread: int4 idx load + float4 nontemporal store (streamed out)
    for (int e = threadIdx.x * 4; e < M_ * S_; e += 256 * 4) {
        const int4 ii = *(const int4*)(ib + e);
        vf4 w;
        w.x = slice[ii.x]; w.y = slice[ii.y];
        w.z = slice[ii.z]; w.w = slice[ii.w];
        __builtin_nontemporal_store(w, (vf4*)(ob + e));
    }
}

// ---- Fallback: round-1 fused kernel (if ws too small) ----------------------
__global__ __launch_bounds__(256) void qg_fused(
    const float* __restrict__ xyz,
    const float* __restrict__ new_xyz,
    const float* __restrict__ features,
    float* __restrict__ out)
{
    const int bm = blockIdx.x;
    const int b  = bm >> 10;
    const int m  = bm & (M_ - 1);
    const int tid = threadIdx.x;

    __shared__ int s_idx[S_];

    if (tid < 64) {
        const int lane = tid;
        const float cx = new_xyz[bm * 3 + 0];
        const float cy = new_xyz[bm * 3 + 1];
        const float cz = new_xyz[bm * 3 + 2];
        const float r2 = (float)(0.3 * 0.3);
        const float* xb = xyz + (size_t)b * N_ * 3;

        int cnt = 0;
        for (int base = 0; base < N_; base += 64) {
            const int n = base + lane;
            bool valid = false;
            if (n < N_) {
                const float dx = __fadd_rn(xb[n * 3 + 0], -cx);
                const float dy = __fadd_rn(xb[n * 3 + 1], -cy);
                const float dz = __fadd_rn(xb[n * 3 + 2], -cz);
                const float d2 = __fadd_rn(
                    __fadd_rn(__fmul_rn(dx, dx), __fmul_rn(dy, dy)),
                    __fmul_rn(dz, dz));
                valid = d2 < r2;
            }
            const unsigned long long mk = __ballot(valid);
            if (valid) {
                const int pos = cnt + __popcll(mk & ((1ull << lane) - 1ull));
                if (pos < S_) s_idx[pos] = n;
            }
            cnt += __popcll(mk);
            if (cnt >= S_) break;
        }
        const int c = cnt < S_ ? cnt : S_;
        const int first = (c > 0) ? s_idx[0] : 0;
        if (lane >= c) s_idx[lane] = first;

        float* out_idx = out + (size_t)B_ * NCH_ * M_ * S_;
        out_idx[(size_t)bm * S_ + lane] = (float)s_idx[lane];
    }
    __syncthreads();

    if (tid < 3 * S_) {
        const int ch = tid >> 6;
        const int s  = tid & 63;
        const int n  = s_idx[s];
        const float v = (xyz[((size_t)b * N_ + n) * 3 + ch] - new_xyz[bm * 3 + ch]) / 0.3f;
        out[(((size_t)b * NCH_ + ch) * M_ + m) * S_ + s] = v;
    }

    const int s  = tid & 63;
    const int cq = tid >> 6;
    const int n  = s_idx[s];
    const float* fb = features + (size_t)b * C_ * N_;
    float* ob = out + (((size_t)b * NCH_ + 3) * M_ + m) * S_ + s;
    for (int ch = cq; ch < C_; ch += 4) {
        ob[(size_t)ch * (M_ * S_)] = fb[(size_t)ch * N_ + n];
    }
}

extern "C" void kernel_launch(void* const* d_in, const int* in_sizes, int n_in,
                              void* d_out, int out_size, void* d_ws, size_t ws_size,
                              hipStream_t stream) {
    const float* xyz      = (const float*)d_in[0];
    const float* new_xyz  = (const float*)d_in[1];
    // d_in[2] = batch_distances, d_in[3] = inds : acceleration hints only, unused
    const float* features = (const float*)d_in[4];
    float* out = (float*)d_out;

    const size_t need = (size_t)B_ * M_ * S_ * sizeof(int);  // 2 MB
    if (ws_size < need) {
        qg_fused<<<B_ * M_, 256, 0, stream>>>(xyz, new_xyz, features, out);
        return;
    }
    int* iws = (int*)d_ws;

    query_kernel<<<B_ * M_, 256, 0, stream>>>(xyz, new_xyz, out, iws);
    group_feat_kernel<<<B_ * C_, 256, 0, stream>>>(features, iws, out);
}